// Round 26
// baseline (28.314 us; speedup 1.0000x reference)
//
#include <hip/hip_runtime.h>

// CGP coupler, duo+quad packed, NT memory, half-wave b128, MAX OCCUPANCY.
//
// Structure (validated R3-R25): runs of 32 entries = segments
//   out[:, 32*ob:32*ob+32] += cg * x1[:, a:a+32] * x2[:, b:b+32]
// nseg ~ 580, nob = 280, counts c in 0..7 (avg ~2), 32-aligned.
//
// R25 lesson: start-up overhead theory dead (3 fusion variants null);
// plateau is in-loop latency. Occupancy audit: EVERY variant since R15
// ran 16 waves/CU = 4 waves/SIMD (R18's "2 blocks/CU" halved block size
// too — never raised total waves). This kernel: ROWS=4, 1024 threads,
// grid 512 -> 2 blocks/CU x 16 waves = 32 waves/CU = 8 waves/SIMD (max).
// Half-wave desc ownership (R17), descs in global (scalar loads; LDS
// stays 32 KB so 2 blocks fit), NT single-use traffic + pk-f32 math (R24).

#define IN_DIM  1024
#define ROWS    4
#define NOBCAP  512
#define SKIP_OB 511u

typedef float f32x2 __attribute__((ext_vector_type(2)));
typedef float f32x4 __attribute__((ext_vector_type(4)));

// ---- prep (1 block, 1024 thr): count -> packed shuffle scan -> fill ----
__global__ __launch_bounds__(1024) void prep_kernel(
    const int* __restrict__ r1, const int* __restrict__ r2,
    const int* __restrict__ ro, const float* __restrict__ cg,
    int nseg, int nob,
    uint2* __restrict__ qdesc, uint2* __restrict__ ddesc,
    int* __restrict__ zlist, int* __restrict__ hdr)
{
    __shared__ int cntS[NOBCAP], rankS[NOBCAP];
    __shared__ int qoffS[NOBCAP], doffS[NOBCAP];
    __shared__ int wsum[8], woff[8];
    const int t = threadIdx.x;

    if (t < NOBCAP) { cntS[t] = 0; rankS[t] = 0; }
    __syncthreads();

    for (int s = t; s < nseg; s += 1024)
        atomicAdd(&cntS[ro[s << 5] >> 5], 1);
    __syncthreads();

    // packed per-ob value: q(quads)<<20 | d(is-duo)<<10 | z(is-shared)
    int c = 0;
    unsigned int pv = 0;
    if (t < NOBCAP) {
        c = (t < nob) ? cntS[t] : 0;
        const int q  = (t < nob && c >= 3) ? ((c + 3) >> 2) : 0;
        const int df = (t < nob && c <= 2) ? 1 : 0;
        const int zf = (t < nob && c > 4) ? 1 : 0;
        pv = ((unsigned int)q << 20) | ((unsigned int)df << 10) | (unsigned int)zf;
    }
    const int lane = t & 63;
    const int wid  = t >> 6;
    #pragma unroll
    for (int off = 1; off < 64; off <<= 1) {
        const unsigned int n = __shfl_up(pv, off, 64);
        if (lane >= off) pv += n;
    }
    if (t < NOBCAP && lane == 63) wsum[wid] = (int)pv;
    __syncthreads();
    if (t < 8) {
        unsigned int v = (unsigned int)wsum[t];
        const unsigned int self = v;
        #pragma unroll
        for (int off = 1; off < 8; off <<= 1) {
            const unsigned int n = __shfl_up(v, off, 64);
            if (t >= off) v += n;
        }
        woff[t] = (int)(v - self);
    }
    __syncthreads();

    if (t < NOBCAP) {
        const unsigned int incl = pv + (unsigned int)woff[wid];
        const int qi = (incl >> 20) & 1023;
        const int di = (incl >> 10) & 1023;
        const int zi = incl & 1023;
        if (t < nob) {
            if (c <= 2) {                                   // duo ob (incl empty)
                const int db = di - 1;
                doffS[t] = db;
                const unsigned int pd = ((unsigned int)t << 20) | 0x80000000u;
                for (int j = (db << 1) + c; j < ((db + 1) << 1); ++j)
                    ddesc[j] = make_uint2(pd, 0u);          // pad: cg=0
            } else {                                        // quad ob
                const int qn = (c + 3) >> 2;
                const int qb = qi - qn;
                qoffS[t] = qb;
                const unsigned int fl = (c > 4) ? 0u : 0x80000000u;
                if (c > 4) zlist[zi - 1] = t;
                const unsigned int pd = ((unsigned int)t << 20) | fl;
                for (int j = (qb << 2) + c; j < ((qb + qn) << 2); ++j)
                    qdesc[j] = make_uint2(pd, 0u);
            }
        }
        if (t == NOBCAP - 1) {
            const int nq = qi, nd = di;
            const int nqPad = (nq + 31) & ~31;              // 16 waves x 2 quads/iter
            const int ndPad = (nd + 63) & ~63;              // 16 waves x 4 duos/iter
            const uint2 dummy = make_uint2(SKIP_OB << 20, 0u);  // terminal skipped
            for (int j = (nq << 2); j < (nqPad << 2); ++j) qdesc[j] = dummy;
            for (int j = (nd << 1); j < (ndPad << 1); ++j) ddesc[j] = dummy;
            hdr[0] = nqPad; hdr[1] = zi; hdr[2] = ndPad;
        }
    }
    __syncthreads();

    for (int s = t; s < nseg; s += 1024) {
        const int k  = s << 5;
        const int ob = ro[k] >> 5;
        const int cc = cntS[ob];
        const int rk = atomicAdd(&rankS[ob], 1);
        const unsigned int fl = (cc > 4) ? 0u : 0x80000000u;
        const uint2 v = make_uint2((unsigned int)r1[k] | ((unsigned int)r2[k] << 10)
                                   | ((unsigned int)ob << 20) | fl,
                                   __float_as_uint(cg[k]));
        if (cc <= 2) ddesc[(doffS[ob] << 1) + rk] = v;
        else         qdesc[(qoffS[ob] << 2) + rk] = v;
    }
}

// packed-fp32 accumulate: ds_read_b128 loads, v_pk_mul/v_pk_fma math
__device__ __forceinline__ void accum4(f32x2& lo, f32x2& hi,
                                       unsigned int dx, unsigned int dc,
                                       const float* xs1, const float* xs2)
{
    const float c = __uint_as_float(dc);
    const f32x4 u = *reinterpret_cast<const f32x4*>(xs1 + (dx & 1023u));
    const f32x4 v = *reinterpret_cast<const f32x4*>(xs2 + ((dx >> 10) & 1023u));
    const f32x2 cc  = {c, c};
    const f32x2 u01 = {u.x, u.y}, u23 = {u.z, u.w};
    const f32x2 v01 = {v.x, v.y}, v23 = {v.z, v.w};
    lo += cc * (u01 * v01);      // pk_mul + pk_fma (contract)
    hi += cc * (u23 * v23);
}

__device__ __forceinline__ void terminal(float* orow, unsigned int hx,
                                         f32x2 lo, f32x2 hi)
{
    const int ob = (int)((hx >> 20) & 511u);
    if (ob == (int)SKIP_OB) return;                  // tail pad: no output
    float* p = orow + (ob << 5);
    if (hx >> 31) {
        const f32x4 st = {lo.x, lo.y, hi.x, hi.y};
        __builtin_nontemporal_store(st, reinterpret_cast<f32x4*>(p));
    } else {                                         // shared: native fadd
        unsafeAtomicAdd(p,     lo.x);
        unsafeAtomicAdd(p + 1, lo.y);
        unsafeAtomicAdd(p + 2, hi.x);
        unsafeAtomicAdd(p + 3, hi.y);
    }
}

// ---- main: 4 rows, 1024 thr, 16 waves; lane = half x row(2b) x f4grp(3b).
//      grid 512 -> 2 blocks/CU -> 32 waves/CU = 8 waves/SIMD (chip max). ----
__global__ __launch_bounds__(1024, 8) void cgp_main(const float* __restrict__ x1,
    const float* __restrict__ x2, const uint2* __restrict__ qdesc,
    const uint2* __restrict__ ddesc, const int* __restrict__ zlist,
    const int* __restrict__ hdr, float* __restrict__ out, int out_dim)
{
    __shared__ float x1s[ROWS * IN_DIM];             // 16 KB
    __shared__ float x2s[ROWS * IN_DIM];             // 16 KB
    const int r0  = blockIdx.x * ROWS;
    const int tid = threadIdx.x;

    {
        const f32x4* p1 = reinterpret_cast<const f32x4*>(x1 + (size_t)r0 * IN_DIM);
        const f32x4* p2 = reinterpret_cast<const f32x4*>(x2 + (size_t)r0 * IN_DIM);
        f32x4* s1 = reinterpret_cast<f32x4*>(x1s);
        f32x4* s2 = reinterpret_cast<f32x4*>(x2s);
        if (tid < (ROWS * IN_DIM) >> 2) {            // 1024 f32x4 per array
            s1[tid] = __builtin_nontemporal_load(p1 + tid);
            s2[tid] = __builtin_nontemporal_load(p2 + tid);
        }
    }
    const int nz = hdr[1];
    for (int i = tid; i < (nz << 5); i += 1024) {    // pre-zero shared obs
        const int ob = zlist[i >> 5];
        const int ch = i & 31;
        float* p = out + (size_t)r0 * out_dim + (ob << 5) + ch;
        #pragma unroll
        for (int j = 0; j < ROWS; ++j)
            __builtin_nontemporal_store(0.f, p + j * out_dim);
    }
    __syncthreads();

    const int w  = tid >> 6;                         // wave 0..15
    const int ln = tid & 63;
    const bool hi = (ln >> 5) != 0;                  // half-wave select
    const int hl = ln & 31;
    const int rr = hl >> 3;                          // row 0..3
    const int tt = hl & 7;                           // float4-channel group
    const float* xs1 = x1s + rr * IN_DIM + (tt << 2);
    const float* xs2 = x2s + rr * IN_DIM + (tt << 2);
    float* orow = out + (size_t)(r0 + rr) * out_dim + (tt << 2);

    // ---- quad loop: 2 quads per wave-iter (one per half) ----
    {
        const int qpw = hdr[0] >> 4;                 // quads per wave (even)
        const uint2* qd = qdesc + ((size_t)(w * qpw) << 2);
        for (int i = 0; i < qpw; i += 2, qd += 8) {
            const uint4 A0 = *reinterpret_cast<const uint4*>(qd);
            const uint4 B0 = *reinterpret_cast<const uint4*>(qd + 2);
            const uint4 A1 = *reinterpret_cast<const uint4*>(qd + 4);
            const uint4 B1 = *reinterpret_cast<const uint4*>(qd + 6);
            const uint4 A  = hi ? A1 : A0;
            const uint4 Bq = hi ? B1 : B0;
            f32x2 lo = {0.f, 0.f}, hh = {0.f, 0.f};
            accum4(lo, hh, A.x,  A.y,  xs1, xs2);
            accum4(lo, hh, A.z,  A.w,  xs1, xs2);
            accum4(lo, hh, Bq.x, Bq.y, xs1, xs2);
            accum4(lo, hh, Bq.z, Bq.w, xs1, xs2);
            terminal(orow, A.x, lo, hh);
        }
    }

    // ---- duo loop: 4 duos per wave-iter (a duo-pair per half) ----
    {
        const int dpw = hdr[2] >> 4;                 // duos per wave (mult of 4)
        const uint2* dd = ddesc + ((size_t)(w * dpw) << 1);
        for (int i = 0; i < dpw; i += 4, dd += 8) {
            const uint4 A0 = *reinterpret_cast<const uint4*>(dd);
            const uint4 B0 = *reinterpret_cast<const uint4*>(dd + 2);
            const uint4 A1 = *reinterpret_cast<const uint4*>(dd + 4);
            const uint4 B1 = *reinterpret_cast<const uint4*>(dd + 6);
            const uint4 A  = hi ? A1 : A0;
            const uint4 Bq = hi ? B1 : B0;
            f32x2 l0 = {0.f, 0.f}, h0 = {0.f, 0.f};
            f32x2 l1 = {0.f, 0.f}, h1 = {0.f, 0.f};
            accum4(l0, h0, A.x,  A.y,  xs1, xs2);
            accum4(l0, h0, A.z,  A.w,  xs1, xs2);
            accum4(l1, h1, Bq.x, Bq.y, xs1, xs2);
            accum4(l1, h1, Bq.z, Bq.w, xs1, xs2);
            terminal(orow, A.x,  l0, h0);
            terminal(orow, Bq.x, l1, h1);
        }
    }
}

extern "C" void kernel_launch(void* const* d_in, const int* in_sizes, int n_in,
                              void* d_out, int out_size, void* d_ws, size_t ws_size,
                              hipStream_t stream)
{
    const float* x1 = (const float*)d_in[0];
    const float* x2 = (const float*)d_in[1];
    const float* cg = (const float*)d_in[2];
    const int*   r1 = (const int*)d_in[3];
    const int*   r2 = (const int*)d_in[4];
    const int*   ro = (const int*)d_in[5];
    float* out = (float*)d_out;

    const int B       = in_sizes[0] / IN_DIM;   // 2048
    const int out_dim = out_size / B;           // 8960
    const int K       = in_sizes[2];
    const int nseg    = K >> 5;                 // ~580
    const int nob     = out_dim >> 5;           // 280
    const int qcap    = nob + (nseg >> 2) + 64; // quad capacity upper bound
    const int dcap    = nob + 96;               // duo capacity upper bound

    auto align16 = [](size_t v) { return (v + 15) & ~(size_t)15; };
    char* ws = (char*)d_ws;
    uint2* qdesc = (uint2*)ws;  ws += align16((size_t)qcap * 4 * sizeof(uint2));
    uint2* ddesc = (uint2*)ws;  ws += align16((size_t)dcap * 2 * sizeof(uint2));
    int*   zlist = (int*)ws;    ws += align16((size_t)NOBCAP * sizeof(int));
    int*   hdr   = (int*)ws;

    hipLaunchKernelGGL(prep_kernel, dim3(1), dim3(1024), 0, stream,
                       r1, r2, ro, cg, nseg, nob, qdesc, ddesc, zlist, hdr);
    hipLaunchKernelGGL(cgp_main, dim3(B / ROWS), dim3(1024), 0, stream,
                       x1, x2, qdesc, ddesc, zlist, hdr, out, out_dim);
}

// Round 27
// 26.150 us; speedup vs baseline: 1.0828x; 1.0828x over previous
//
#include <hip/hip_runtime.h>

// CGP coupler, ONE-DISPATCH fused form with register-staged overlap.
// REVERT to R25 (best measured: 26.39 us) after R26's max-occupancy
// experiment regressed (28.3 us: 8 waves/SIMD doubles DS/store-pipe
// contention with no latency left to hide).
//
// Structure (validated R3-R26): runs of 32 entries = segments
//   out[:, 32*ob:32*ob+32] += cg * x1[:, a:a+32] * x2[:, b:b+32]
// nseg ~ 580 (<=1024), nob = 280, counts c in 0..7 (avg ~2), 32-aligned.
//
// Final design: single dispatch; per-block local prep in LDS (count ->
// packed shuffle scan -> duo/quad pack -> fill) overlapped with register
// NT staging of the 64 KB row tile via lgkm-only barriers; compute =
// fat-body quad + duo-pair loops, b128 LDS gathers, pk-f32 math, NT
// terminal stores, native global fadd for the few shared obs.

#define IN_DIM  1024
#define ROWS    8
#define NOBCAP  512
#define SKIP_OB 511u
#define QSLOTS  1024
#define DSLOTS  640

typedef float f32x2 __attribute__((ext_vector_type(2)));
typedef float f32x4 __attribute__((ext_vector_type(4)));

// lgkm-only barrier: orders LDS ops across the block without draining vmem
#define BAR_LDS() do { asm volatile("s_waitcnt lgkmcnt(0)" ::: "memory"); \
                       __builtin_amdgcn_s_barrier(); } while (0)
// full drain barrier (global stores/loads + LDS visible)
#define BAR_ALL() do { asm volatile("s_waitcnt vmcnt(0) lgkmcnt(0)" ::: "memory"); \
                       __builtin_amdgcn_s_barrier(); } while (0)

__device__ __forceinline__ void accum4(f32x2& lo, f32x2& hi,
                                       unsigned int dx, unsigned int dc,
                                       const float* xs1, const float* xs2)
{
    const float c = __uint_as_float(dc);
    const f32x4 u = *reinterpret_cast<const f32x4*>(xs1 + (dx & 1023u));
    const f32x4 v = *reinterpret_cast<const f32x4*>(xs2 + ((dx >> 10) & 1023u));
    const f32x2 cc  = {c, c};
    const f32x2 u01 = {u.x, u.y}, u23 = {u.z, u.w};
    const f32x2 v01 = {v.x, v.y}, v23 = {v.z, v.w};
    lo += cc * (u01 * v01);      // v_pk_mul + v_pk_fma
    hi += cc * (u23 * v23);
}

__device__ __forceinline__ void terminal(float* orow, unsigned int hx,
                                         f32x2 lo, f32x2 hi)
{
    const int ob = (int)((hx >> 20) & 511u);
    if (ob == (int)SKIP_OB) return;                  // tail pad: no output
    float* p = orow + (ob << 5);
    if (hx >> 31) {
        const f32x4 st = {lo.x, lo.y, hi.x, hi.y};
        __builtin_nontemporal_store(st, reinterpret_cast<f32x4*>(p));
    } else {                                         // shared: native fadd
        unsafeAtomicAdd(p,     lo.x);
        unsafeAtomicAdd(p + 1, lo.y);
        unsafeAtomicAdd(p + 2, hi.x);
        unsafeAtomicAdd(p + 3, hi.y);
    }
}

__global__ __launch_bounds__(1024) void cgp_fused(
    const float* __restrict__ x1, const float* __restrict__ x2,
    const int* __restrict__ r1, const int* __restrict__ r2,
    const int* __restrict__ ro, const float* __restrict__ cg,
    int nseg, int nob, float* __restrict__ out, int out_dim)
{
    __shared__ __align__(16) float x1s[ROWS * IN_DIM];   // 32 KB
    __shared__ __align__(16) float x2s[ROWS * IN_DIM];   // 32 KB
    __shared__ __align__(16) uint2 qdescL[QSLOTS];       // 8 KB
    __shared__ __align__(16) uint2 ddescL[DSLOTS];       // 5 KB
    __shared__ int cntS[NOBCAP], rankS[NOBCAP];          // 4 KB
    __shared__ int qoffS[NOBCAP], doffS[NOBCAP];         // 4 KB
    __shared__ int wsum[8], woff[8];
    __shared__ int zlistL[128];
    __shared__ int hdrL[4];

    const int t  = threadIdx.x;                          // 0..1023
    const int r0 = blockIdx.x * ROWS;

    // ---- zero counters first (LDS only, no loads yet) ----
    if (t < NOBCAP) { cntS[t] = 0; rankS[t] = 0; }

    // ---- prep global loads: ONE round covers nseg <= 1024 ----
    int roV = 0, r1V = 0, r2V = 0; float cgV = 0.f;
    if (t < nseg) {
        const int k = t << 5;
        roV = ro[k]; r1V = r1[k]; r2V = r2[k]; cgV = cg[k];
    }

    // ---- staging loads into REGISTERS (issued after prep loads; their
    //      drain is deferred to the regs->LDS write below) ----
    const f32x4* p1 = reinterpret_cast<const f32x4*>(x1 + (size_t)r0 * IN_DIM);
    const f32x4* p2 = reinterpret_cast<const f32x4*>(x2 + (size_t)r0 * IN_DIM);
    const f32x4 sA = __builtin_nontemporal_load(p1 + t);
    const f32x4 sB = __builtin_nontemporal_load(p1 + t + 1024);
    const f32x4 sC = __builtin_nontemporal_load(p2 + t);
    const f32x4 sD = __builtin_nontemporal_load(p2 + t + 1024);

    BAR_LDS();                                           // zeros visible

    // ---- count (LDS int atomics; waits only on prep loads) ----
    for (int s = t; s < nseg; s += 1024)
        atomicAdd(&cntS[((s == t) ? roV : ro[s << 5]) >> 5], 1);
    BAR_LDS();

    // ---- packed shuffle scan over 512 ob slots (threads 0..511) ----
    int c = 0; unsigned int pv = 0;
    if (t < NOBCAP) {
        c = (t < nob) ? cntS[t] : 0;
        const int q  = (t < nob && c >= 3) ? ((c + 3) >> 2) : 0;
        const int df = (t < nob && c <= 2) ? 1 : 0;
        const int zf = (t < nob && c > 4) ? 1 : 0;
        pv = ((unsigned int)q << 20) | ((unsigned int)df << 10) | (unsigned int)zf;
    }
    const int lane = t & 63, wid = t >> 6;
    #pragma unroll
    for (int off = 1; off < 64; off <<= 1) {
        const unsigned int n = __shfl_up(pv, off, 64);
        if (lane >= off) pv += n;
    }
    if (t < NOBCAP && lane == 63) wsum[wid] = (int)pv;
    BAR_LDS();
    if (t < 8) {
        unsigned int v = (unsigned int)wsum[t];
        const unsigned int self = v;
        #pragma unroll
        for (int off = 1; off < 8; off <<= 1) {
            const unsigned int n = __shfl_up(v, off, 64);
            if (t >= off) v += n;
        }
        woff[t] = (int)(v - self);
    }
    BAR_LDS();

    // ---- per-ob offsets, pads, hdr, zlist ----
    if (t < NOBCAP) {
        const unsigned int incl = pv + (unsigned int)woff[wid];
        const int qi = (incl >> 20) & 1023;
        const int di = (incl >> 10) & 1023;
        const int zi = incl & 1023;
        if (t < nob) {
            if (c <= 2) {                                // duo ob (incl empty)
                const int db = di - 1;
                doffS[t] = db;
                const unsigned int pd = ((unsigned int)t << 20) | 0x80000000u;
                for (int j = (db << 1) + c; j < ((db + 1) << 1); ++j)
                    ddescL[j] = make_uint2(pd, 0u);      // pad: cg=0
            } else {                                     // quad ob
                const int qn = (c + 3) >> 2;
                const int qb = qi - qn;
                qoffS[t] = qb;
                const unsigned int fl = (c > 4) ? 0u : 0x80000000u;
                if (c > 4) zlistL[zi - 1] = t;
                const unsigned int pd = ((unsigned int)t << 20) | fl;
                for (int j = (qb << 2) + c; j < ((qb + qn) << 2); ++j)
                    qdescL[j] = make_uint2(pd, 0u);
            }
        }
        if (t == NOBCAP - 1) {
            const int nq = qi, nd = di;
            const int nqPad = (nq + 15) & ~15;           // 16 quads (1/wave)
            const int ndPad = (nd + 31) & ~31;           // 32 duos (pair/wave)
            const uint2 dummy = make_uint2(SKIP_OB << 20, 0u);
            for (int j = (nq << 2); j < (nqPad << 2); ++j) qdescL[j] = dummy;
            for (int j = (nd << 1); j < (ndPad << 1); ++j) ddescL[j] = dummy;
            hdrL[0] = nqPad; hdrL[1] = zi; hdrL[2] = ndPad;
        }
    }
    BAR_LDS();

    // ---- fill real descriptors into LDS (values preloaded) ----
    for (int s = t; s < nseg; s += 1024) {
        int ob, rv1, rv2; float cgx;
        if (s == t) { ob = roV >> 5; rv1 = r1V; rv2 = r2V; cgx = cgV; }
        else { const int k = s << 5; ob = ro[k] >> 5; rv1 = r1[k]; rv2 = r2[k]; cgx = cg[k]; }
        const int cc = cntS[ob];
        const int rk = atomicAdd(&rankS[ob], 1);
        const unsigned int fl = (cc > 4) ? 0u : 0x80000000u;
        const uint2 v = make_uint2((unsigned int)rv1 | ((unsigned int)rv2 << 10)
                                   | ((unsigned int)ob << 20) | fl,
                                   __float_as_uint(cgx));
        if (cc <= 2) ddescL[(doffS[ob] << 1) + rk] = v;
        else         qdescL[(qoffS[ob] << 2) + rk] = v;
    }

    // ---- regs -> LDS (staging vmem drains here via value deps) ----
    {
        f32x4* s1 = reinterpret_cast<f32x4*>(x1s);
        f32x4* s2 = reinterpret_cast<f32x4*>(x2s);
        s1[t] = sA; s1[t + 1024] = sB;
        s2[t] = sC; s2[t + 1024] = sD;
    }

    // ---- pre-zero shared obs (needs hdr/zlist: ordered by prior BAR_LDS) ----
    const int nz = hdrL[1];
    for (int i = t; i < (nz << 5); i += 1024) {
        const int ob = zlistL[i >> 5], ch = i & 31;
        float* p = out + (size_t)r0 * out_dim + (ob << 5) + ch;
        #pragma unroll
        for (int j = 0; j < ROWS; ++j)
            __builtin_nontemporal_store(0.f, p + j * out_dim);
    }
    BAR_ALL();   // zeros + LDS rows + descs all visible before compute

    // ---- compute (fat-body loops, descriptors from LDS) ----
    const int w  = t >> 6;                               // wave 0..15
    const int ln = t & 63;
    const int rr = ln >> 3;                              // row 0..7
    const int tt = ln & 7;                               // float4-group
    const float* xs1 = x1s + rr * IN_DIM + (tt << 2);
    const float* xs2 = x2s + rr * IN_DIM + (tt << 2);
    float* orow = out + (size_t)(r0 + rr) * out_dim + (tt << 2);

    // quad loop (obs with c>=3)
    {
        const int qpw = hdrL[0] >> 4;
        const uint2* qd = qdescL + ((size_t)(w * qpw) << 2);
        #pragma unroll 2
        for (int i = 0; i < qpw; ++i, qd += 4) {
            const uint4 A  = *reinterpret_cast<const uint4*>(qd);
            const uint4 Bq = *reinterpret_cast<const uint4*>(qd + 2);
            f32x2 lo = {0.f, 0.f}, hi = {0.f, 0.f};
            accum4(lo, hi, A.x,  A.y,  xs1, xs2);
            accum4(lo, hi, A.z,  A.w,  xs1, xs2);
            accum4(lo, hi, Bq.x, Bq.y, xs1, xs2);
            accum4(lo, hi, Bq.z, Bq.w, xs1, xs2);
            terminal(orow, A.x, lo, hi);
        }
    }
    // duo-pair loop (obs with c<=2)
    {
        const int ppw = hdrL[2] >> 5;
        const uint2* dd = ddescL + ((size_t)(w * ppw) << 2);
        #pragma unroll 2
        for (int i = 0; i < ppw; ++i, dd += 4) {
            const uint4 A  = *reinterpret_cast<const uint4*>(dd);
            const uint4 Bq = *reinterpret_cast<const uint4*>(dd + 2);
            f32x2 l0 = {0.f, 0.f}, h0 = {0.f, 0.f};
            f32x2 l1 = {0.f, 0.f}, h1 = {0.f, 0.f};
            accum4(l0, h0, A.x,  A.y,  xs1, xs2);
            accum4(l0, h0, A.z,  A.w,  xs1, xs2);
            accum4(l1, h1, Bq.x, Bq.y, xs1, xs2);
            accum4(l1, h1, Bq.z, Bq.w, xs1, xs2);
            terminal(orow, A.x,  l0, h0);
            terminal(orow, Bq.x, l1, h1);
        }
    }
}

extern "C" void kernel_launch(void* const* d_in, const int* in_sizes, int n_in,
                              void* d_out, int out_size, void* d_ws, size_t ws_size,
                              hipStream_t stream)
{
    const float* x1 = (const float*)d_in[0];
    const float* x2 = (const float*)d_in[1];
    const float* cg = (const float*)d_in[2];
    const int*   r1 = (const int*)d_in[3];
    const int*   r2 = (const int*)d_in[4];
    const int*   ro = (const int*)d_in[5];
    float* out = (float*)d_out;

    const int B       = in_sizes[0] / IN_DIM;   // 2048
    const int out_dim = out_size / B;           // 8960
    const int K       = in_sizes[2];
    const int nseg    = K >> 5;                 // ~580 (<= 1024)
    const int nob     = out_dim >> 5;           // 280

    hipLaunchKernelGGL(cgp_fused, dim3(B / ROWS), dim3(1024), 0, stream,
                       x1, x2, r1, r2, ro, cg, nseg, nob, out, out_dim);
}